// Round 1
// baseline (372.933 us; speedup 1.0000x reference)
//
#include <hip/hip_runtime.h>
#include <math.h>

#define BB 2
#define CC 256
#define NHEAD 8
#define HD 32
#define NGRP 8
#define NNTOK 32768
#define ATT_EPS 1e-6f
#define GN_EPS 1e-5f
#define KB_GN 64

typedef __attribute__((ext_vector_type(8))) short bfrag8;   // 8 bf16
typedef __attribute__((ext_vector_type(4))) float accf4;    // MFMA C/D 16x16

__device__ __forceinline__ float b2f(unsigned short u) {
    unsigned int x = ((unsigned int)u) << 16;
    return __uint_as_float(x);
}
__device__ __forceinline__ unsigned short f2b(float f) {
    unsigned int x = __float_as_uint(f);
    unsigned int r = x + 0x7fffu + ((x >> 16) & 1u);
    return (unsigned short)(r >> 16);
}
__device__ __forceinline__ void gl_lds16(const void* g, void* s) {
    __builtin_amdgcn_global_load_lds(
        (const __attribute__((address_space(1))) unsigned int*)g,
        (__attribute__((address_space(3))) unsigned int*)s, 16, 0, 0);
}

// ---- workspace layout (float offsets) — identical to the verified round-2 map ----
#define WS_QMT   0ull            // bf16 [B][H][N][32]
#define WS_XNT   (WS_QMT + 8388608ull)    // bf16 [B][N][264] padded
#define WS_WST   (WS_XNT + 8650752ull)    // bf16 [H][96][264] padded
#define WS_PART  (WS_WST + 101632ull)     // f32 [16 bh][256 tiles][1056]
#define WS_GNP   (WS_PART + 4325376ull)
#define WS_SCALE (WS_GNP + 2048ull)
#define WS_SHIFT (WS_SCALE + 512ull)
#define WS_CTX   (WS_SHIFT + 512ull)      // (unused, kept for layout stability)
#define WS_KSUM  (WS_CTX + 16384ull)      // f32 [B][H][32]
#define WS_AMAT  (WS_KSUM + 512ull)       // bf16 [B][256][256]
#define WS_DEN   (WS_AMAT + 65536ull)     // f32 region; part2 aliases this
#define WS_PART2 WS_DEN                   // f32 [16 bh][16][1056] = 270336 < 524288

// LDS for qkv_ctx (dynamic, 67584 B): xs 128x528 staged; after barrier overlay:
// kmv 64x272 @0, qs 128x80 @17408, ksp @27648
#define LDS_QS_OFF  17408
#define LDS_KSP_OFF 27648
#define LDS_QKV_TOTAL 67584

// ============ Kernel 1: GroupNorm partial sums (R2 verbatim) ============
__global__ __launch_bounds__(256) void gn_stats(const float* __restrict__ x,
                                                float* __restrict__ part) {
    int grp = blockIdx.x / KB_GN;
    int blk = blockIdx.x % KB_GN;
    const float* base = x + (size_t)grp * (CC / NGRP) * NNTOK + (size_t)blk * 16384;
    int t = threadIdx.x;
    float s = 0.f, s2 = 0.f;
    for (int i = 0; i < 16; ++i) {
        const float4 v = *(const float4*)(base + i * 1024 + t * 4);
        s  += v.x + v.y + v.z + v.w;
        s2 += v.x * v.x + v.y * v.y + v.z * v.z + v.w * v.w;
    }
    for (int off = 32; off; off >>= 1) {
        s  += __shfl_down(s, off);
        s2 += __shfl_down(s2, off);
    }
    __shared__ float ls[4], ls2[4];
    int wave = t >> 6;
    if ((t & 63) == 0) { ls[wave] = s; ls2[wave] = s2; }
    __syncthreads();
    if (t == 0) {
        part[(grp * KB_GN + blk) * 2 + 0] = ls[0] + ls[1] + ls[2] + ls[3];
        part[(grp * KB_GN + blk) * 2 + 1] = ls2[0] + ls2[1] + ls2[2] + ls2[3];
    }
}

// ============ Kernel 2: finalize GN (R2 verbatim) ============
__global__ __launch_bounds__(256) void gn_finalize(const float* __restrict__ part,
                                                   const float* __restrict__ gamma,
                                                   const float* __restrict__ beta,
                                                   float* __restrict__ scale,
                                                   float* __restrict__ shift) {
    __shared__ float mean_s[16], rstd_s[16];
    int t = threadIdx.x;
    if (t < 16) {
        float s = 0.f, s2 = 0.f;
        for (int i = 0; i < KB_GN; ++i) {
            s  += part[(t * KB_GN + i) * 2 + 0];
            s2 += part[(t * KB_GN + i) * 2 + 1];
        }
        const float inv = 1.0f / (float)((CC / NGRP) * NNTOK);
        float m = s * inv;
        float var = s2 * inv - m * m;
        mean_s[t] = m;
        rstd_s[t] = rsqrtf(var + GN_EPS);
    }
    __syncthreads();
    for (int idx = t; idx < BB * CC; idx += 256) {
        int b = idx / CC, c = idx % CC;
        int grp = b * NGRP + c / (CC / NGRP);
        float sc = gamma[c] * rstd_s[grp];
        scale[idx] = sc;
        shift[idx] = beta[c] - mean_s[grp] * sc;
    }
}

// ============ Kernel 3: Wst[h][96][264] bf16 padded (R2 verbatim) ============
__global__ __launch_bounds__(256) void prep_w(const float* __restrict__ wq,
                                              const float* __restrict__ wk,
                                              const float* __restrict__ wv,
                                              unsigned short* __restrict__ Wst) {
    int h = blockIdx.x, t = threadIdx.x;
    const float* Ws[3] = {wq, wk, wv};
    for (int i = t; i < 96 * 264; i += 256) {
        int r = i / 264, c = i % 264;
        float v = 0.f;
        if (c < 256) v = Ws[r >> 5][(size_t)(h * 32 + (r & 31)) * CC + c];
        Wst[(size_t)h * (96 * 264) + i] = f2b(v);
    }
}

// ============ Kernel 4: xn_t[b][n][264] bf16 (R2 verbatim) ============
__global__ __launch_bounds__(256) void xn_prep(const float* __restrict__ x,
                                               const float* __restrict__ scale,
                                               const float* __restrict__ shift,
                                               unsigned short* __restrict__ xn_t) {
    __shared__ unsigned short xt[64][264];
    int b = blockIdx.y, n0 = blockIdx.x * 64, t = threadIdx.x;
    int col4 = (t & 15) * 4;
    for (int i = 0; i < 16; ++i) {
        int c = (t >> 4) + i * 16;
        float sc = scale[b * CC + c], sh = shift[b * CC + c];
        const float4 v = *(const float4*)(x + (size_t)(b * CC + c) * NNTOK + n0 + col4);
        xt[col4 + 0][c] = f2b(v.x * sc + sh);
        xt[col4 + 1][c] = f2b(v.y * sc + sh);
        xt[col4 + 2][c] = f2b(v.z * sc + sh);
        xt[col4 + 3][c] = f2b(v.w * sc + sh);
    }
    __syncthreads();
    int n = t >> 2, q = t & 3;
    const char* src = (const char*)&xt[n][0] + q * 128;
    char* dst = (char*)(xn_t + ((size_t)b * NNTOK + n0 + n) * 264) + q * 128;
    #pragma unroll
    for (int i = 0; i < 8; ++i)
        *(float4*)(dst + i * 16) = *(const float4*)(src + i * 16);
}

// ============ Kernel 5: fused QKV MFMA + elu + ctx/ksum partials ============
// Same dataflow as the verified R2 structure, now 512 threads (8 waves): each
// wave owns 16 tokens in the main loop, LDS unchanged (67.6 KB, 2 blocks/CU)
// => 16 waves/CU resident instead of 8. Context (waves 0-3) and ksum partials
// (waves 4-7) run concurrently in the epilogue.
__global__ __launch_bounds__(512, 4) void qkv_ctx(
    const unsigned short* __restrict__ xn_t, const unsigned short* __restrict__ Wst,
    unsigned short* __restrict__ qm_t, float* __restrict__ part) {
    extern __shared__ char lds[];
    const int tile = blockIdx.x, h = blockIdx.y, b = blockIdx.z;
    const int t = threadIdx.x;
    const int lane = t & 63, w = t >> 6;        // w in 0..7
    const int lr = lane & 15, lq = lane >> 4;
    const int n0 = tile * 128;

    // stage xn tile (128 x 528 B) via global_load_lds
    {
        const char* xg = (const char*)(xn_t + ((size_t)b * NNTOK + n0) * 264);
        for (int j = w; j < 66; j += 8)
            gl_lds16(xg + j * 1024 + lane * 16, lds + j * 1024);
    }
    __syncthreads();

    accf4 acc[6];
    #pragma unroll
    for (int i = 0; i < 6; ++i) acc[i] = (accf4){0.f, 0.f, 0.f, 0.f};

    const unsigned short* Wg = Wst + (size_t)h * (96 * 264);
    const char* xl = lds;
    // prefetch W frags for kc=0 (same addressing math as verified version)
    bfrag8 wnx[6];
    #pragma unroll
    for (int mi = 0; mi < 6; ++mi)
        wnx[mi] = *(const bfrag8*)(Wg + (mi * 16 + lr) * 264 + lq * 8);

    const int nn = w * 16 + lr;                 // this thread's token row
    #pragma unroll
    for (int kc = 0; kc < 8; ++kc) {
        bfrag8 wcur[6];
        #pragma unroll
        for (int mi = 0; mi < 6; ++mi) wcur[mi] = wnx[mi];
        if (kc < 7) {
            #pragma unroll
            for (int mi = 0; mi < 6; ++mi)
                wnx[mi] = *(const bfrag8*)(Wg + (mi * 16 + lr) * 264 + (kc + 1) * 32 + lq * 8);
        }
        bfrag8 bfr = *(const bfrag8*)(xl + nn * 528 + kc * 64 + lq * 16);
        #pragma unroll
        for (int mi = 0; mi < 6; ++mi)
            acc[mi] = __builtin_amdgcn_mfma_f32_16x16x32_bf16(wcur[mi], bfr, acc[mi], 0, 0, 0);
    }
    __syncthreads();   // all waves done reading xs — overlay region now safe

    // epilogue (overlay pointers)
    char* kmv = lds;                 // km rows 0..31, v rows 32..63, stride 272
    char* qs  = lds + LDS_QS_OFF;    // qm [n 128][80 B]
    #pragma unroll
    for (int mi = 0; mi < 2; ++mi)
        #pragma unroll
        for (int r = 0; r < 4; ++r) {
            int d = mi * 16 + lq * 4 + r;
            float q = acc[mi][r];
            *(unsigned short*)(qs + nn * 80 + d * 2) = f2b(q > 0.f ? q + 1.f : __expf(q));
        }
    #pragma unroll
    for (int mi = 2; mi < 4; ++mi)
        #pragma unroll
        for (int r = 0; r < 4; ++r) {
            int d = (mi - 2) * 16 + lq * 4 + r;
            float kk = acc[mi][r];
            *(unsigned short*)(kmv + d * 272 + nn * 2) = f2b(kk > 0.f ? kk + 1.f : __expf(kk));
        }
    #pragma unroll
    for (int mi = 4; mi < 6; ++mi)
        #pragma unroll
        for (int r = 0; r < 4; ++r) {
            int e = (mi - 4) * 16 + lq * 4 + r;
            *(unsigned short*)(kmv + (32 + e) * 272 + nn * 2) = f2b(acc[mi][r]);
        }
    __syncthreads();

    const size_t pb = (size_t)((b * NHEAD + h) * 256 + tile) * 1056;

    // qm -> global (512 threads, 16B each)
    {
        char* qg = (char*)(qm_t + ((size_t)(b * NHEAD + h) * NNTOK + n0) * 32);
        int n = t >> 2, qh = t & 3;
        *(float4*)(qg + n * 64 + qh * 16) = *(const float4*)(qs + n * 80 + qh * 16);
    }

    // context quadrant on waves 0..3; ksum partials on waves 4..7 (concurrent)
    if (w < 4) {
        int qr = w >> 1, qc = w & 1;
        accf4 cacc = (accf4){0.f, 0.f, 0.f, 0.f};
        #pragma unroll
        for (int kk = 0; kk < 4; ++kk) {
            bfrag8 a  = *(const bfrag8*)(kmv + (qr * 16 + lr) * 272 + kk * 64 + lq * 16);
            bfrag8 bb = *(const bfrag8*)(kmv + (32 + qc * 16 + lr) * 272 + kk * 64 + lq * 16);
            cacc = __builtin_amdgcn_mfma_f32_16x16x32_bf16(a, bb, cacc, 0, 0, 0);
        }
        #pragma unroll
        for (int r = 0; r < 4; ++r) {
            int d = qr * 16 + lq * 4 + r, e = qc * 16 + lr;
            part[pb + d * 32 + e] = cacc[r];
        }
    } else {
        float* ksp = (float*)(lds + LDS_KSP_OFF);
        int t2 = t - 256;
        int d = t2 >> 3, oc = t2 & 7;
        float s = 0.f;
        for (int i = 0; i < 16; ++i)
            s += b2f(*(const unsigned short*)(kmv + d * 272 + (oc * 16 + i) * 2));
        ksp[d * 8 + oc] = s;
    }
    __syncthreads();
    if (t < 32) {
        float* ksp = (float*)(lds + LDS_KSP_OFF);
        float s2 = 0.f;
        #pragma unroll
        for (int i = 0; i < 8; ++i) s2 += ksp[t * 8 + i];
        part[pb + 1024 + t] = s2;
    }
}

// ============ Kernel 6: reduce 256 tile-records -> 16 per bh ============
__global__ __launch_bounds__(256) void reduce1(const float* __restrict__ part,
                                               float* __restrict__ part2) {
    int chunk = blockIdx.x, bh = blockIdx.y, t = threadIdx.x;
    const float* p = part + ((size_t)bh * 256 + chunk * 16) * 1056;
    for (int i = t; i < 1056; i += 256) {
        float s = 0.f;
        #pragma unroll
        for (int j = 0; j < 16; ++j) s += p[(size_t)j * 1056 + i];
        part2[((size_t)bh * 16 + chunk) * 1056 + i] = s;
    }
}

// ============ Kernel 7: build A (bf16) + finalize ksum ============
__global__ __launch_bounds__(256) void build_A(const float* __restrict__ w_out,
                                               const float* __restrict__ part2,
                                               unsigned short* __restrict__ Amat,
                                               float* __restrict__ ksum_g) {
    int ot = blockIdx.x, b = blockIdx.y, t = threadIdx.x;
    __shared__ float cs[NHEAD * HD * HD];
    for (int i = t; i < NHEAD * HD * HD; i += 256) {
        int hh = i >> 10, de = i & 1023;
        const float* p2 = part2 + (size_t)(b * NHEAD + hh) * 16 * 1056;
        float s = 0.f;
        #pragma unroll
        for (int c16 = 0; c16 < 16; ++c16) s += p2[(size_t)c16 * 1056 + de];
        cs[i] = s;
    }
    if (ot == 0) {
        const float* p2 = part2 + (size_t)(b * NHEAD + (t >> 5)) * 16 * 1056;
        float s = 0.f;
        #pragma unroll
        for (int c16 = 0; c16 < 16; ++c16) s += p2[(size_t)c16 * 1056 + 1024 + (t & 31)];
        ksum_g[b * CC + t] = s;
    }
    __syncthreads();
    int h = t >> 5, d = t & 31;
    for (int oi = 0; oi < 32; ++oi) {
        int o = ot * 32 + oi;
        const float* wrow = w_out + (size_t)o * CC + h * HD;
        float s = 0.f;
        #pragma unroll
        for (int e = 0; e < HD; ++e) s += wrow[e] * cs[h * 1024 + d * 32 + e];
        Amat[((size_t)(b * CC + o)) * CC + t] = f2b(s);
    }
}

// ============ Kernel 8: out = A @ (qm*den) + b_out + x, den fused in ============
#define LDSF_A   0
#define LDSF_Q   10240
#define LDSF_DEN 20480
#define LDSF_BO  20992
__global__ __launch_bounds__(256, 2) void final_out(
    const unsigned short* __restrict__ qm_t, const unsigned short* __restrict__ Amat,
    const float* __restrict__ ksum_g, const float* __restrict__ b_out,
    const float* __restrict__ x, float* __restrict__ out) {
    __shared__ char L[21504];
    int tile = blockIdx.x, mt = blockIdx.y, b = blockIdx.z;
    int n0 = tile * 128, t = threadIdx.x;
    int lane = t & 63, w = t >> 6, lr = lane & 15, lq = lane >> 4;
    int wm = (w >> 1) * 64, wn = (w & 1) * 64;
    accf4 acc[4][4];
    #pragma unroll
    for (int i = 0; i < 4; ++i)
        #pragma unroll
        for (int j = 0; j < 4; ++j) acc[i][j] = (accf4){0.f, 0.f, 0.f, 0.f};

    if (t < 128) ((float*)(L + LDSF_BO))[t] = b_out[mt * 128 + t];

    char* Al = L + LDSF_A;
    char* Ql = L + LDSF_Q;
    for (int h = 0; h < NHEAD; ++h) {
        int m = t >> 1, half = t & 1;
        const char* ag = (const char*)(Amat + ((size_t)(b * CC + mt * 128 + m) * CC + h * 32)) + half * 32;
        float4 av0 = *(const float4*)ag, av1 = *(const float4*)(ag + 16);
        const char* qg = (const char*)(qm_t + ((size_t)(b * NHEAD + h) * NNTOK + n0 + m) * 32) + half * 32;
        float4 qv0 = *(const float4*)qg, qv1 = *(const float4*)(qg + 16);
        float ksv = 0.f;
        if (t < 32) ksv = ksum_g[b * CC + h * 32 + t];
        __syncthreads();
        *(float4*)(Al + m * 80 + half * 32) = av0;
        *(float4*)(Al + m * 80 + half * 32 + 16) = av1;
        *(float4*)(Ql + m * 80 + half * 32) = qv0;
        *(float4*)(Ql + m * 80 + half * 32 + 16) = qv1;
        if (t < 32) ((float*)(L + LDSF_DEN))[t] = ksv;
        __syncthreads();
        {
            // fused den: dot(qm row, ksum) via pair of half-dots + shfl_xor
            int n = t >> 1, u = t & 1;
            const float* ksL = (const float*)(L + LDSF_DEN);
            char* p = Ql + n * 80 + u * 32;
            bfrag8 v0 = *(bfrag8*)p, v1 = *(bfrag8*)(p + 16);
            float sp = 0.f;
            #pragma unroll
            for (int e = 0; e < 8; ++e) {
                sp += b2f((unsigned short)v0[e]) * ksL[u * 16 + e];
                sp += b2f((unsigned short)v1[e]) * ksL[u * 16 + 8 + e];
            }
            float dot = sp + __shfl_xor(sp, 1);
            float dn = 1.0f / (dot + ATT_EPS);
            #pragma unroll
            for (int e = 0; e < 8; ++e) {
                v0[e] = (short)f2b(b2f((unsigned short)v0[e]) * dn);
                v1[e] = (short)f2b(b2f((unsigned short)v1[e]) * dn);
            }
            *(bfrag8*)p = v0;
            *(bfrag8*)(p + 16) = v1;
        }
        __syncthreads();
        bfrag8 bfr[4];
        #pragma unroll
        for (int ci = 0; ci < 4; ++ci) {
            int n = wn + ci * 16 + lr;
            bfr[ci] = *(const bfrag8*)(Ql + n * 80 + lq * 16);
        }
        #pragma unroll
        for (int mi = 0; mi < 4; ++mi) {
            bfrag8 a = *(const bfrag8*)(Al + (wm + mi * 16 + lr) * 80 + lq * 16);
            #pragma unroll
            for (int ci = 0; ci < 4; ++ci)
                acc[mi][ci] = __builtin_amdgcn_mfma_f32_16x16x32_bf16(a, bfr[ci], acc[mi][ci], 0, 0, 0);
        }
        __syncthreads();
    }

    const float* bo_s = (const float*)(L + LDSF_BO);
    #pragma unroll
    for (int mi = 0; mi < 4; ++mi)
        #pragma unroll
        for (int ci = 0; ci < 4; ++ci)
            #pragma unroll
            for (int r = 0; r < 4; ++r) {
                int ol = wm + mi * 16 + lq * 4 + r;
                int n = wn + ci * 16 + lr;
                size_t idx = ((size_t)(b * CC + mt * 128 + ol)) * NNTOK + n0 + n;
                out[idx] = acc[mi][ci][r] + bo_s[ol] + x[idx];
            }
}

extern "C" void kernel_launch(void* const* d_in, const int* in_sizes, int n_in,
                              void* d_out, int out_size, void* d_ws, size_t ws_size,
                              hipStream_t stream) {
    (void)in_sizes; (void)n_in; (void)out_size; (void)ws_size;
    const float* x      = (const float*)d_in[0];
    const float* gamma  = (const float*)d_in[1];
    const float* beta   = (const float*)d_in[2];
    const float* wq     = (const float*)d_in[3];
    const float* wk     = (const float*)d_in[4];
    const float* wv     = (const float*)d_in[5];
    const float* w_out  = (const float*)d_in[6];
    const float* b_out  = (const float*)d_in[7];
    float* out = (float*)d_out;
    float* ws  = (float*)d_ws;

    unsigned short* qm_t = (unsigned short*)(ws + WS_QMT);
    unsigned short* xn_t = (unsigned short*)(ws + WS_XNT);
    unsigned short* Wst  = (unsigned short*)(ws + WS_WST);
    float* part  = ws + WS_PART;
    float* part2 = ws + WS_PART2;   // aliases den region (read before any reuse)
    float* gnp   = ws + WS_GNP;
    float* scale = ws + WS_SCALE;
    float* shift = ws + WS_SHIFT;
    float* ksum  = ws + WS_KSUM;
    unsigned short* Amat = (unsigned short*)(ws + WS_AMAT);

    hipFuncSetAttribute((const void*)qkv_ctx,
                        hipFuncAttributeMaxDynamicSharedMemorySize, LDS_QKV_TOTAL);

    hipLaunchKernelGGL(gn_stats, dim3(BB * NGRP * KB_GN), dim3(256), 0, stream, x, gnp);
    hipLaunchKernelGGL(gn_finalize, dim3(1), dim3(256), 0, stream, gnp, gamma, beta, scale, shift);
    hipLaunchKernelGGL(prep_w, dim3(NHEAD), dim3(256), 0, stream, wq, wk, wv, Wst);
    hipLaunchKernelGGL(xn_prep, dim3(NNTOK / 64, BB), dim3(256), 0, stream, x, scale, shift, xn_t);
    hipLaunchKernelGGL(qkv_ctx, dim3(NNTOK / 128, NHEAD, BB), dim3(512), LDS_QKV_TOTAL, stream,
                       xn_t, Wst, qm_t, part);
    hipLaunchKernelGGL(reduce1, dim3(16, 16), dim3(256), 0, stream, part, part2);
    hipLaunchKernelGGL(build_A, dim3(8, BB), dim3(256), 0, stream, w_out, part2, Amat, ksum);
    hipLaunchKernelGGL(final_out, dim3(NNTOK / 128, 2, BB), dim3(256), 0, stream,
                       qm_t, Amat, ksum, b_out, x, out);
}

// Round 2
// 332.381 us; speedup vs baseline: 1.1220x; 1.1220x over previous
//
#include <hip/hip_runtime.h>
#include <math.h>

#define BB 2
#define CC 256
#define NHEAD 8
#define HD 32
#define NGRP 8
#define NNTOK 32768
#define ATT_EPS 1e-6f
#define GN_EPS 1e-5f
#define KB_GN 64

typedef __attribute__((ext_vector_type(8))) short bfrag8;   // 8 bf16
typedef __attribute__((ext_vector_type(4))) float accf4;    // MFMA C/D 16x16

__device__ __forceinline__ float b2f(unsigned short u) {
    unsigned int x = ((unsigned int)u) << 16;
    return __uint_as_float(x);
}
__device__ __forceinline__ unsigned short f2b(float f) {
    unsigned int x = __float_as_uint(f);
    unsigned int r = x + 0x7fffu + ((x >> 16) & 1u);
    return (unsigned short)(r >> 16);
}

// ---- workspace layout (float offsets) — identical to the verified round-2 map ----
#define WS_QMT   0ull            // bf16 [B][H][N][32]
#define WS_XNT   (WS_QMT + 8388608ull)    // bf16 [B][N][264] padded
#define WS_WST   (WS_XNT + 8650752ull)    // bf16 [H][96][264] padded
#define WS_PART  (WS_WST + 101632ull)     // f32 [16 bh][256 tiles][1056]
#define WS_GNP   (WS_PART + 4325376ull)
#define WS_SCALE (WS_GNP + 2048ull)
#define WS_SHIFT (WS_SCALE + 512ull)
#define WS_CTX   (WS_SHIFT + 512ull)      // (unused, kept for layout stability)
#define WS_KSUM  (WS_CTX + 16384ull)      // f32 [B][H][32]
#define WS_AMAT  (WS_KSUM + 512ull)       // bf16 [B][256][256]
#define WS_DEN   (WS_AMAT + 65536ull)     // f32 region; part2 aliases this
#define WS_PART2 WS_DEN                   // f32 [16 bh][16][1056] = 270336 < 524288

// LDS for qkv_ctx (static, 28672 B): kmv 64x272 @0, qs 128x80 @17408, ksp @27648
#define LDS_QS_OFF  17408
#define LDS_KSP_OFF 27648
#define LDS_QKV_TOTAL 28672

// ============ Kernel 1: GroupNorm partial sums (R2 verbatim) ============
__global__ __launch_bounds__(256) void gn_stats(const float* __restrict__ x,
                                                float* __restrict__ part) {
    int grp = blockIdx.x / KB_GN;
    int blk = blockIdx.x % KB_GN;
    const float* base = x + (size_t)grp * (CC / NGRP) * NNTOK + (size_t)blk * 16384;
    int t = threadIdx.x;
    float s = 0.f, s2 = 0.f;
    for (int i = 0; i < 16; ++i) {
        const float4 v = *(const float4*)(base + i * 1024 + t * 4);
        s  += v.x + v.y + v.z + v.w;
        s2 += v.x * v.x + v.y * v.y + v.z * v.z + v.w * v.w;
    }
    for (int off = 32; off; off >>= 1) {
        s  += __shfl_down(s, off);
        s2 += __shfl_down(s2, off);
    }
    __shared__ float ls[4], ls2[4];
    int wave = t >> 6;
    if ((t & 63) == 0) { ls[wave] = s; ls2[wave] = s2; }
    __syncthreads();
    if (t == 0) {
        part[(grp * KB_GN + blk) * 2 + 0] = ls[0] + ls[1] + ls[2] + ls[3];
        part[(grp * KB_GN + blk) * 2 + 1] = ls2[0] + ls2[1] + ls2[2] + ls2[3];
    }
}

// ============ Kernel 2: finalize GN (R2 verbatim) ============
__global__ __launch_bounds__(256) void gn_finalize(const float* __restrict__ part,
                                                   const float* __restrict__ gamma,
                                                   const float* __restrict__ beta,
                                                   float* __restrict__ scale,
                                                   float* __restrict__ shift) {
    __shared__ float mean_s[16], rstd_s[16];
    int t = threadIdx.x;
    if (t < 16) {
        float s = 0.f, s2 = 0.f;
        for (int i = 0; i < KB_GN; ++i) {
            s  += part[(t * KB_GN + i) * 2 + 0];
            s2 += part[(t * KB_GN + i) * 2 + 1];
        }
        const float inv = 1.0f / (float)((CC / NGRP) * NNTOK);
        float m = s * inv;
        float var = s2 * inv - m * m;
        mean_s[t] = m;
        rstd_s[t] = rsqrtf(var + GN_EPS);
    }
    __syncthreads();
    for (int idx = t; idx < BB * CC; idx += 256) {
        int b = idx / CC, c = idx % CC;
        int grp = b * NGRP + c / (CC / NGRP);
        float sc = gamma[c] * rstd_s[grp];
        scale[idx] = sc;
        shift[idx] = beta[c] - mean_s[grp] * sc;
    }
}

// ============ Kernel 3: Wst[h][96][264] bf16 padded (R2 verbatim) ============
__global__ __launch_bounds__(256) void prep_w(const float* __restrict__ wq,
                                              const float* __restrict__ wk,
                                              const float* __restrict__ wv,
                                              unsigned short* __restrict__ Wst) {
    int h = blockIdx.x, t = threadIdx.x;
    const float* Ws[3] = {wq, wk, wv};
    for (int i = t; i < 96 * 264; i += 256) {
        int r = i / 264, c = i % 264;
        float v = 0.f;
        if (c < 256) v = Ws[r >> 5][(size_t)(h * 32 + (r & 31)) * CC + c];
        Wst[(size_t)h * (96 * 264) + i] = f2b(v);
    }
}

// ============ Kernel 4: xn_t[b][n][264] bf16 (R2 verbatim) ============
__global__ __launch_bounds__(256) void xn_prep(const float* __restrict__ x,
                                               const float* __restrict__ scale,
                                               const float* __restrict__ shift,
                                               unsigned short* __restrict__ xn_t) {
    __shared__ unsigned short xt[64][264];
    int b = blockIdx.y, n0 = blockIdx.x * 64, t = threadIdx.x;
    int col4 = (t & 15) * 4;
    for (int i = 0; i < 16; ++i) {
        int c = (t >> 4) + i * 16;
        float sc = scale[b * CC + c], sh = shift[b * CC + c];
        const float4 v = *(const float4*)(x + (size_t)(b * CC + c) * NNTOK + n0 + col4);
        xt[col4 + 0][c] = f2b(v.x * sc + sh);
        xt[col4 + 1][c] = f2b(v.y * sc + sh);
        xt[col4 + 2][c] = f2b(v.z * sc + sh);
        xt[col4 + 3][c] = f2b(v.w * sc + sh);
    }
    __syncthreads();
    int n = t >> 2, q = t & 3;
    const char* src = (const char*)&xt[n][0] + q * 128;
    char* dst = (char*)(xn_t + ((size_t)b * NNTOK + n0 + n) * 264) + q * 128;
    #pragma unroll
    for (int i = 0; i < 8; ++i)
        *(float4*)(dst + i * 16) = *(const float4*)(src + i * 16);
}

// ============ Kernel 5: fused QKV MFMA + elu + ctx/ksum partials ============
// R0-verified 256-thread / 12-MFMA-per-kc structure, but NO xn LDS staging:
// each thread's B-frag is a 16B-aligned slice of its own xn_t row, read
// directly from global (L2/L3-resident) with 1-kc-ahead prefetch, same as W.
// LDS drops 67.6 -> 28.7 KB (epilogue only) => 3 blocks/CU, no stage barrier.
__global__ __launch_bounds__(256, 3) void qkv_ctx(
    const unsigned short* __restrict__ xn_t, const unsigned short* __restrict__ Wst,
    unsigned short* __restrict__ qm_t, float* __restrict__ part) {
    __shared__ char lds[LDS_QKV_TOTAL];
    const int tile = blockIdx.x, h = blockIdx.y, b = blockIdx.z;
    const int t = threadIdx.x;
    const int lane = t & 63, w = t >> 6;
    const int lr = lane & 15, lq = lane >> 4;
    const int n0 = tile * 128;

    accf4 acc[6][2];
    #pragma unroll
    for (int i = 0; i < 6; ++i)
        #pragma unroll
        for (int j = 0; j < 2; ++j) acc[i][j] = (accf4){0.f, 0.f, 0.f, 0.f};

    const unsigned short* Wg = Wst + (size_t)h * (96 * 264);
    // this thread's two xn_t rows (ci=0,1); 16B chunk selected by lq, kc
    const unsigned short* xr0 = xn_t + ((size_t)b * NNTOK + n0 + w * 32 + lr) * 264 + lq * 8;
    const unsigned short* xr1 = xr0 + 16 * 264;

    // prefetch kc=0 fragments (W addressing identical to verified version)
    bfrag8 wnx[6], bnx[2];
    #pragma unroll
    for (int mi = 0; mi < 6; ++mi)
        wnx[mi] = *(const bfrag8*)(Wg + (mi * 16 + lr) * 264 + lq * 8);
    bnx[0] = *(const bfrag8*)xr0;
    bnx[1] = *(const bfrag8*)xr1;

    #pragma unroll
    for (int kc = 0; kc < 8; ++kc) {
        bfrag8 wcur[6];
        #pragma unroll
        for (int mi = 0; mi < 6; ++mi) wcur[mi] = wnx[mi];
        bfrag8 bcur[2] = {bnx[0], bnx[1]};
        if (kc < 7) {
            #pragma unroll
            for (int mi = 0; mi < 6; ++mi)
                wnx[mi] = *(const bfrag8*)(Wg + (mi * 16 + lr) * 264 + (kc + 1) * 32 + lq * 8);
            bnx[0] = *(const bfrag8*)(xr0 + (kc + 1) * 32);
            bnx[1] = *(const bfrag8*)(xr1 + (kc + 1) * 32);
        }
        #pragma unroll
        for (int mi = 0; mi < 6; ++mi)
            #pragma unroll
            for (int ci = 0; ci < 2; ++ci)
                acc[mi][ci] = __builtin_amdgcn_mfma_f32_16x16x32_bf16(wcur[mi], bcur[ci], acc[mi][ci], 0, 0, 0);
    }

    // epilogue (R0 verbatim; LDS is private to this phase, no pre-barrier needed)
    char* kmv = lds;                 // km rows 0..31, v rows 32..63, stride 272
    char* qs  = lds + LDS_QS_OFF;    // qm [n 128][80 B]
    #pragma unroll
    for (int mi = 0; mi < 2; ++mi)
        #pragma unroll
        for (int ci = 0; ci < 2; ++ci)
            #pragma unroll
            for (int r = 0; r < 4; ++r) {
                int d = mi * 16 + lq * 4 + r;
                int n = w * 32 + ci * 16 + lr;
                float q = acc[mi][ci][r];
                *(unsigned short*)(qs + n * 80 + d * 2) = f2b(q > 0.f ? q + 1.f : __expf(q));
            }
    #pragma unroll
    for (int mi = 2; mi < 4; ++mi)
        #pragma unroll
        for (int ci = 0; ci < 2; ++ci)
            #pragma unroll
            for (int r = 0; r < 4; ++r) {
                int d = (mi - 2) * 16 + lq * 4 + r;
                int n = w * 32 + ci * 16 + lr;
                float kk = acc[mi][ci][r];
                *(unsigned short*)(kmv + d * 272 + n * 2) = f2b(kk > 0.f ? kk + 1.f : __expf(kk));
            }
    #pragma unroll
    for (int mi = 4; mi < 6; ++mi)
        #pragma unroll
        for (int ci = 0; ci < 2; ++ci)
            #pragma unroll
            for (int r = 0; r < 4; ++r) {
                int e = (mi - 4) * 16 + lq * 4 + r;
                int n = w * 32 + ci * 16 + lr;
                *(unsigned short*)(kmv + (32 + e) * 272 + n * 2) = f2b(acc[mi][ci][r]);
            }
    __syncthreads();

    const size_t pb = (size_t)((b * NHEAD + h) * 256 + tile) * 1056;

    // qm -> global (R0 verbatim)
    {
        char* qg = (char*)(qm_t + ((size_t)(b * NHEAD + h) * NNTOK + n0) * 32);
        int n = t >> 1, half = t & 1;
        const char* src = qs + n * 80 + half * 32;
        char* dst = qg + n * 64 + half * 32;
        *(float4*)dst = *(const float4*)src;
        *(float4*)(dst + 16) = *(const float4*)(src + 16);
    }

    // context quadrant per wave, K=128 (R0 verbatim)
    {
        int qr = w >> 1, qc = w & 1;
        accf4 cacc = (accf4){0.f, 0.f, 0.f, 0.f};
        #pragma unroll
        for (int kk = 0; kk < 4; ++kk) {
            bfrag8 a  = *(const bfrag8*)(kmv + (qr * 16 + lr) * 272 + kk * 64 + lq * 16);
            bfrag8 bb = *(const bfrag8*)(kmv + (32 + qc * 16 + lr) * 272 + kk * 64 + lq * 16);
            cacc = __builtin_amdgcn_mfma_f32_16x16x32_bf16(a, bb, cacc, 0, 0, 0);
        }
        #pragma unroll
        for (int r = 0; r < 4; ++r) {
            int d = qr * 16 + lq * 4 + r, e = qc * 16 + lr;
            part[pb + d * 32 + e] = cacc[r];
        }
    }

    // ksum partial (R0 verbatim)
    {
        float* ksp = (float*)(lds + LDS_KSP_OFF);
        int d = t >> 3, oc = t & 7;
        float s = 0.f;
        for (int i = 0; i < 16; ++i)
            s += b2f(*(const unsigned short*)(kmv + d * 272 + (oc * 16 + i) * 2));
        ksp[d * 8 + oc] = s;
        __syncthreads();
        if (t < 32) {
            float s2 = 0.f;
            #pragma unroll
            for (int i = 0; i < 8; ++i) s2 += ksp[t * 8 + i];
            part[pb + 1024 + t] = s2;
        }
    }
}

// ============ Kernel 6: reduce 256 tile-records -> 16 per bh ============
__global__ __launch_bounds__(256) void reduce1(const float* __restrict__ part,
                                               float* __restrict__ part2) {
    int chunk = blockIdx.x, bh = blockIdx.y, t = threadIdx.x;
    const float* p = part + ((size_t)bh * 256 + chunk * 16) * 1056;
    for (int i = t; i < 1056; i += 256) {
        float s = 0.f;
        #pragma unroll
        for (int j = 0; j < 16; ++j) s += p[(size_t)j * 1056 + i];
        part2[((size_t)bh * 16 + chunk) * 1056 + i] = s;
    }
}

// ============ Kernel 7: build A (bf16) + finalize ksum ============
__global__ __launch_bounds__(256) void build_A(const float* __restrict__ w_out,
                                               const float* __restrict__ part2,
                                               unsigned short* __restrict__ Amat,
                                               float* __restrict__ ksum_g) {
    int ot = blockIdx.x, b = blockIdx.y, t = threadIdx.x;
    __shared__ float cs[NHEAD * HD * HD];
    for (int i = t; i < NHEAD * HD * HD; i += 256) {
        int hh = i >> 10, de = i & 1023;
        const float* p2 = part2 + (size_t)(b * NHEAD + hh) * 16 * 1056;
        float s = 0.f;
        #pragma unroll
        for (int c16 = 0; c16 < 16; ++c16) s += p2[(size_t)c16 * 1056 + de];
        cs[i] = s;
    }
    if (ot == 0) {
        const float* p2 = part2 + (size_t)(b * NHEAD + (t >> 5)) * 16 * 1056;
        float s = 0.f;
        #pragma unroll
        for (int c16 = 0; c16 < 16; ++c16) s += p2[(size_t)c16 * 1056 + 1024 + (t & 31)];
        ksum_g[b * CC + t] = s;
    }
    __syncthreads();
    int h = t >> 5, d = t & 31;
    for (int oi = 0; oi < 32; ++oi) {
        int o = ot * 32 + oi;
        const float* wrow = w_out + (size_t)o * CC + h * HD;
        float s = 0.f;
        #pragma unroll
        for (int e = 0; e < HD; ++e) s += wrow[e] * cs[h * 1024 + d * 32 + e];
        Amat[((size_t)(b * CC + o)) * CC + t] = f2b(s);
    }
}

// ============ Kernel 8: out = A @ (qm*den) + b_out + x, den fused in ============
#define LDSF_A   0
#define LDSF_Q   10240
#define LDSF_DEN 20480
#define LDSF_BO  20992
__global__ __launch_bounds__(256, 2) void final_out(
    const unsigned short* __restrict__ qm_t, const unsigned short* __restrict__ Amat,
    const float* __restrict__ ksum_g, const float* __restrict__ b_out,
    const float* __restrict__ x, float* __restrict__ out) {
    __shared__ char L[21504];
    int tile = blockIdx.x, mt = blockIdx.y, b = blockIdx.z;
    int n0 = tile * 128, t = threadIdx.x;
    int lane = t & 63, w = t >> 6, lr = lane & 15, lq = lane >> 4;
    int wm = (w >> 1) * 64, wn = (w & 1) * 64;
    accf4 acc[4][4];
    #pragma unroll
    for (int i = 0; i < 4; ++i)
        #pragma unroll
        for (int j = 0; j < 4; ++j) acc[i][j] = (accf4){0.f, 0.f, 0.f, 0.f};

    if (t < 128) ((float*)(L + LDSF_BO))[t] = b_out[mt * 128 + t];

    char* Al = L + LDSF_A;
    char* Ql = L + LDSF_Q;
    for (int h = 0; h < NHEAD; ++h) {
        int m = t >> 1, half = t & 1;
        const char* ag = (const char*)(Amat + ((size_t)(b * CC + mt * 128 + m) * CC + h * 32)) + half * 32;
        float4 av0 = *(const float4*)ag, av1 = *(const float4*)(ag + 16);
        const char* qg = (const char*)(qm_t + ((size_t)(b * NHEAD + h) * NNTOK + n0 + m) * 32) + half * 32;
        float4 qv0 = *(const float4*)qg, qv1 = *(const float4*)(qg + 16);
        float ksv = 0.f;
        if (t < 32) ksv = ksum_g[b * CC + h * 32 + t];
        __syncthreads();
        *(float4*)(Al + m * 80 + half * 32) = av0;
        *(float4*)(Al + m * 80 + half * 32 + 16) = av1;
        *(float4*)(Ql + m * 80 + half * 32) = qv0;
        *(float4*)(Ql + m * 80 + half * 32 + 16) = qv1;
        if (t < 32) ((float*)(L + LDSF_DEN))[t] = ksv;
        __syncthreads();
        {
            // fused den: dot(qm row, ksum) via pair of half-dots + shfl_xor
            int n = t >> 1, u = t & 1;
            const float* ksL = (const float*)(L + LDSF_DEN);
            char* p = Ql + n * 80 + u * 32;
            bfrag8 v0 = *(bfrag8*)p, v1 = *(bfrag8*)(p + 16);
            float sp = 0.f;
            #pragma unroll
            for (int e = 0; e < 8; ++e) {
                sp += b2f((unsigned short)v0[e]) * ksL[u * 16 + e];
                sp += b2f((unsigned short)v1[e]) * ksL[u * 16 + 8 + e];
            }
            float dot = sp + __shfl_xor(sp, 1);
            float dn = 1.0f / (dot + ATT_EPS);
            #pragma unroll
            for (int e = 0; e < 8; ++e) {
                v0[e] = (short)f2b(b2f((unsigned short)v0[e]) * dn);
                v1[e] = (short)f2b(b2f((unsigned short)v1[e]) * dn);
            }
            *(bfrag8*)p = v0;
            *(bfrag8*)(p + 16) = v1;
        }
        __syncthreads();
        bfrag8 bfr[4];
        #pragma unroll
        for (int ci = 0; ci < 4; ++ci) {
            int n = wn + ci * 16 + lr;
            bfr[ci] = *(const bfrag8*)(Ql + n * 80 + lq * 16);
        }
        #pragma unroll
        for (int mi = 0; mi < 4; ++mi) {
            bfrag8 a = *(const bfrag8*)(Al + (wm + mi * 16 + lr) * 80 + lq * 16);
            #pragma unroll
            for (int ci = 0; ci < 4; ++ci)
                acc[mi][ci] = __builtin_amdgcn_mfma_f32_16x16x32_bf16(a, bfr[ci], acc[mi][ci], 0, 0, 0);
        }
        __syncthreads();
    }

    const float* bo_s = (const float*)(L + LDSF_BO);
    #pragma unroll
    for (int mi = 0; mi < 4; ++mi)
        #pragma unroll
        for (int ci = 0; ci < 4; ++ci)
            #pragma unroll
            for (int r = 0; r < 4; ++r) {
                int ol = wm + mi * 16 + lq * 4 + r;
                int n = wn + ci * 16 + lr;
                size_t idx = ((size_t)(b * CC + mt * 128 + ol)) * NNTOK + n0 + n;
                out[idx] = acc[mi][ci][r] + bo_s[ol] + x[idx];
            }
}

extern "C" void kernel_launch(void* const* d_in, const int* in_sizes, int n_in,
                              void* d_out, int out_size, void* d_ws, size_t ws_size,
                              hipStream_t stream) {
    (void)in_sizes; (void)n_in; (void)out_size; (void)ws_size;
    const float* x      = (const float*)d_in[0];
    const float* gamma  = (const float*)d_in[1];
    const float* beta   = (const float*)d_in[2];
    const float* wq     = (const float*)d_in[3];
    const float* wk     = (const float*)d_in[4];
    const float* wv     = (const float*)d_in[5];
    const float* w_out  = (const float*)d_in[6];
    const float* b_out  = (const float*)d_in[7];
    float* out = (float*)d_out;
    float* ws  = (float*)d_ws;

    unsigned short* qm_t = (unsigned short*)(ws + WS_QMT);
    unsigned short* xn_t = (unsigned short*)(ws + WS_XNT);
    unsigned short* Wst  = (unsigned short*)(ws + WS_WST);
    float* part  = ws + WS_PART;
    float* part2 = ws + WS_PART2;   // aliases den region (read before any reuse)
    float* gnp   = ws + WS_GNP;
    float* scale = ws + WS_SCALE;
    float* shift = ws + WS_SHIFT;
    float* ksum  = ws + WS_KSUM;
    unsigned short* Amat = (unsigned short*)(ws + WS_AMAT);

    hipLaunchKernelGGL(gn_stats, dim3(BB * NGRP * KB_GN), dim3(256), 0, stream, x, gnp);
    hipLaunchKernelGGL(gn_finalize, dim3(1), dim3(256), 0, stream, gnp, gamma, beta, scale, shift);
    hipLaunchKernelGGL(prep_w, dim3(NHEAD), dim3(256), 0, stream, wq, wk, wv, Wst);
    hipLaunchKernelGGL(xn_prep, dim3(NNTOK / 64, BB), dim3(256), 0, stream, x, scale, shift, xn_t);
    hipLaunchKernelGGL(qkv_ctx, dim3(NNTOK / 128, NHEAD, BB), dim3(256), 0, stream,
                       xn_t, Wst, qm_t, part);
    hipLaunchKernelGGL(reduce1, dim3(16, 16), dim3(256), 0, stream, part, part2);
    hipLaunchKernelGGL(build_A, dim3(8, BB), dim3(256), 0, stream, w_out, part2, Amat, ksum);
    hipLaunchKernelGGL(final_out, dim3(NNTOK / 128, 2, BB), dim3(256), 0, stream,
                       qm_t, Amat, ksum, b_out, x, out);
}

// Round 3
// 290.218 us; speedup vs baseline: 1.2850x; 1.1453x over previous
//
#include <hip/hip_runtime.h>
#include <math.h>

#define BB 2
#define CC 256
#define NHEAD 8
#define HD 32
#define NGRP 8
#define NNTOK 32768
#define ATT_EPS 1e-6f
#define GN_EPS 1e-5f
#define KB_GN 64

typedef __attribute__((ext_vector_type(8))) short bfrag8;   // 8 bf16
typedef __attribute__((ext_vector_type(4))) float accf4;    // MFMA C/D 16x16

__device__ __forceinline__ float b2f(unsigned short u) {
    unsigned int x = ((unsigned int)u) << 16;
    return __uint_as_float(x);
}
__device__ __forceinline__ unsigned short f2b(float f) {
    unsigned int x = __float_as_uint(f);
    unsigned int r = x + 0x7fffu + ((x >> 16) & 1u);
    return (unsigned short)(r >> 16);
}
__device__ __forceinline__ void gl_lds16(const void* g, void* s) {
    __builtin_amdgcn_global_load_lds(
        (const __attribute__((address_space(1))) unsigned int*)g,
        (__attribute__((address_space(3))) unsigned int*)s, 16, 0, 0);
}

// ---- workspace layout (float offsets) — identical to the verified map ----
#define WS_QMT   0ull            // bf16 [B][H][N][32]
#define WS_XNT   (WS_QMT + 8388608ull)    // bf16 [B][N][264] padded
#define WS_WST   (WS_XNT + 8650752ull)    // bf16 [H][24576] frag-linear (48KB/head)
#define WS_PART  (WS_WST + 101632ull)     // f32 [16 bh][256 tiles][1056]
#define WS_GNP   (WS_PART + 4325376ull)
#define WS_SCALE (WS_GNP + 2048ull)
#define WS_SHIFT (WS_SCALE + 512ull)
#define WS_CTX   (WS_SHIFT + 512ull)      // (unused, kept for layout stability)
#define WS_KSUM  (WS_CTX + 16384ull)      // f32 [B][H][32]
#define WS_AMAT  (WS_KSUM + 512ull)       // bf16 [B][256][256]
#define WS_DEN   (WS_AMAT + 65536ull)     // f32 region; part2 aliases this
#define WS_PART2 WS_DEN                   // f32 [16 bh][16][1056] = 270336 < 524288

// LDS for qkv_ctx: W tile 48KB frag-linear during main loop; epilogue overlay
// after barrier: kmv 64x272 @0, qs 128x80 @17408, ksp @27648 (29696 <= 49152)
#define LDS_QS_OFF  17408
#define LDS_KSP_OFF 27648
#define LDS_QKV_TOTAL 49152

// ============ Kernel 1: GroupNorm partial sums (verbatim) ============
__global__ __launch_bounds__(256) void gn_stats(const float* __restrict__ x,
                                                float* __restrict__ part) {
    int grp = blockIdx.x / KB_GN;
    int blk = blockIdx.x % KB_GN;
    const float* base = x + (size_t)grp * (CC / NGRP) * NNTOK + (size_t)blk * 16384;
    int t = threadIdx.x;
    float s = 0.f, s2 = 0.f;
    for (int i = 0; i < 16; ++i) {
        const float4 v = *(const float4*)(base + i * 1024 + t * 4);
        s  += v.x + v.y + v.z + v.w;
        s2 += v.x * v.x + v.y * v.y + v.z * v.z + v.w * v.w;
    }
    for (int off = 32; off; off >>= 1) {
        s  += __shfl_down(s, off);
        s2 += __shfl_down(s2, off);
    }
    __shared__ float ls[4], ls2[4];
    int wave = t >> 6;
    if ((t & 63) == 0) { ls[wave] = s; ls2[wave] = s2; }
    __syncthreads();
    if (t == 0) {
        part[(grp * KB_GN + blk) * 2 + 0] = ls[0] + ls[1] + ls[2] + ls[3];
        part[(grp * KB_GN + blk) * 2 + 1] = ls2[0] + ls2[1] + ls2[2] + ls2[3];
    }
}

// ============ Kernel 2: finalize GN (verbatim) ============
__global__ __launch_bounds__(256) void gn_finalize(const float* __restrict__ part,
                                                   const float* __restrict__ gamma,
                                                   const float* __restrict__ beta,
                                                   float* __restrict__ scale,
                                                   float* __restrict__ shift) {
    __shared__ float mean_s[16], rstd_s[16];
    int t = threadIdx.x;
    if (t < 16) {
        float s = 0.f, s2 = 0.f;
        for (int i = 0; i < KB_GN; ++i) {
            s  += part[(t * KB_GN + i) * 2 + 0];
            s2 += part[(t * KB_GN + i) * 2 + 1];
        }
        const float inv = 1.0f / (float)((CC / NGRP) * NNTOK);
        float m = s * inv;
        float var = s2 * inv - m * m;
        mean_s[t] = m;
        rstd_s[t] = rsqrtf(var + GN_EPS);
    }
    __syncthreads();
    for (int idx = t; idx < BB * CC; idx += 256) {
        int b = idx / CC, c = idx % CC;
        int grp = b * NGRP + c / (CC / NGRP);
        float sc = gamma[c] * rstd_s[grp];
        scale[idx] = sc;
        shift[idx] = beta[c] - mean_s[grp] * sc;
    }
}

// ============ Kernel 3: Wst frag-linear: [h][kc][mi][lane][8e] bf16 ============
// Element (h, i): e=i&7, chunk=i>>3, lane=chunk&63, kcmi=chunk>>6, mi=kcmi%6,
// kc=kcmi/6. Frag for (mi,kc) at lane (lr=lane&15,lq=lane>>4) holds
// W[row=mi*16+lr][col=kc*32+lq*8+e], rows 0-31=q, 32-63=k, 64-95=v.
__global__ __launch_bounds__(256) void prep_w(const float* __restrict__ wq,
                                              const float* __restrict__ wk,
                                              const float* __restrict__ wv,
                                              unsigned short* __restrict__ Wst) {
    int h = blockIdx.x, t = threadIdx.x;
    const float* Ws[3] = {wq, wk, wv};
    for (int i = t; i < 24576; i += 256) {
        int e = i & 7;
        int chunk = i >> 3;
        int lane = chunk & 63;
        int kcmi = chunk >> 6;
        int mi = kcmi % 6;
        int kc = kcmi / 6;
        int lr = lane & 15, lq = lane >> 4;
        int row = mi * 16 + lr;
        int col = kc * 32 + lq * 8 + e;
        float v = Ws[row >> 5][(size_t)(h * 32 + (row & 31)) * CC + col];
        Wst[(size_t)h * 24576 + i] = f2b(v);
    }
}

// ============ Kernel 4: xn_t[b][n][264] bf16 (verbatim) ============
__global__ __launch_bounds__(256) void xn_prep(const float* __restrict__ x,
                                               const float* __restrict__ scale,
                                               const float* __restrict__ shift,
                                               unsigned short* __restrict__ xn_t) {
    __shared__ unsigned short xt[64][264];
    int b = blockIdx.y, n0 = blockIdx.x * 64, t = threadIdx.x;
    int col4 = (t & 15) * 4;
    for (int i = 0; i < 16; ++i) {
        int c = (t >> 4) + i * 16;
        float sc = scale[b * CC + c], sh = shift[b * CC + c];
        const float4 v = *(const float4*)(x + (size_t)(b * CC + c) * NNTOK + n0 + col4);
        xt[col4 + 0][c] = f2b(v.x * sc + sh);
        xt[col4 + 1][c] = f2b(v.y * sc + sh);
        xt[col4 + 2][c] = f2b(v.z * sc + sh);
        xt[col4 + 3][c] = f2b(v.w * sc + sh);
    }
    __syncthreads();
    int n = t >> 2, q = t & 3;
    const char* src = (const char*)&xt[n][0] + q * 128;
    char* dst = (char*)(xn_t + ((size_t)b * NNTOK + n0 + n) * 264) + q * 128;
    #pragma unroll
    for (int i = 0; i < 8; ++i)
        *(float4*)(dst + i * 16) = *(const float4*)(src + i * 16);
}

// ============ Kernel 5: fused QKV MFMA + elu + ctx/ksum partials ============
// R2-verified math; W now staged once per block into LDS (48KB frag-linear,
// conflict-free contiguous ds_read_b128), xn direct-global with 1-kc prefetch.
// 1D grid with XCD-chunked swizzle: heads fastest within an XCD so each xn
// tile is fetched once into one XCD's L2 and reused by all 8 heads.
__global__ __launch_bounds__(256, 3) void qkv_ctx(
    const unsigned short* __restrict__ xn_t, const unsigned short* __restrict__ Wst,
    unsigned short* __restrict__ qm_t, float* __restrict__ part) {
    __shared__ char lds[LDS_QKV_TOTAL];
    const int id = blockIdx.x;
    const int xcd = id & 7;
    const int j = id >> 3;
    const int h = j & 7;
    const int rem = j >> 3;                 // 0..63
    const int tile = xcd * 32 + (rem & 31);
    const int b = rem >> 5;
    const int t = threadIdx.x;
    const int lane = t & 63, w = t >> 6;
    const int lr = lane & 15, lq = lane >> 4;
    const int n0 = tile * 128;

    // stage W tile (48KB) frag-linear; LDS dest wave-uniform + lane*16
    {
        const char* wg = (const char*)(Wst + (size_t)h * 24576);
        for (int jj = w; jj < 48; jj += 4)
            gl_lds16(wg + jj * 1024 + lane * 16, lds + jj * 1024);
    }
    __syncthreads();

    accf4 acc[6][2];
    #pragma unroll
    for (int i = 0; i < 6; ++i)
        #pragma unroll
        for (int jj = 0; jj < 2; ++jj) acc[i][jj] = (accf4){0.f, 0.f, 0.f, 0.f};

    // this thread's two xn_t rows (ci=0,1); 16B chunk selected by lq, kc
    const unsigned short* xr0 = xn_t + ((size_t)b * NNTOK + n0 + w * 32 + lr) * 264 + lq * 8;
    const unsigned short* xr1 = xr0 + 16 * 264;
    const char* wl = lds;

    // prefetch kc=0 fragments
    bfrag8 wnx[6], bnx[2];
    #pragma unroll
    for (int mi = 0; mi < 6; ++mi)
        wnx[mi] = *(const bfrag8*)(wl + (0 * 6 + mi) * 1024 + lane * 16);
    bnx[0] = *(const bfrag8*)xr0;
    bnx[1] = *(const bfrag8*)xr1;

    #pragma unroll
    for (int kc = 0; kc < 8; ++kc) {
        bfrag8 wcur[6];
        #pragma unroll
        for (int mi = 0; mi < 6; ++mi) wcur[mi] = wnx[mi];
        bfrag8 bcur[2] = {bnx[0], bnx[1]};
        if (kc < 7) {
            #pragma unroll
            for (int mi = 0; mi < 6; ++mi)
                wnx[mi] = *(const bfrag8*)(wl + ((kc + 1) * 6 + mi) * 1024 + lane * 16);
            bnx[0] = *(const bfrag8*)(xr0 + (kc + 1) * 32);
            bnx[1] = *(const bfrag8*)(xr1 + (kc + 1) * 32);
        }
        #pragma unroll
        for (int mi = 0; mi < 6; ++mi)
            #pragma unroll
            for (int ci = 0; ci < 2; ++ci)
                acc[mi][ci] = __builtin_amdgcn_mfma_f32_16x16x32_bf16(wcur[mi], bcur[ci], acc[mi][ci], 0, 0, 0);
    }
    __syncthreads();   // all waves done reading W region — overlay now safe

    // epilogue (verified math, overlay pointers)
    char* kmv = lds;                 // km rows 0..31, v rows 32..63, stride 272
    char* qs  = lds + LDS_QS_OFF;    // qm [n 128][80 B]
    #pragma unroll
    for (int mi = 0; mi < 2; ++mi)
        #pragma unroll
        for (int ci = 0; ci < 2; ++ci)
            #pragma unroll
            for (int r = 0; r < 4; ++r) {
                int d = mi * 16 + lq * 4 + r;
                int n = w * 32 + ci * 16 + lr;
                float q = acc[mi][ci][r];
                *(unsigned short*)(qs + n * 80 + d * 2) = f2b(q > 0.f ? q + 1.f : __expf(q));
            }
    #pragma unroll
    for (int mi = 2; mi < 4; ++mi)
        #pragma unroll
        for (int ci = 0; ci < 2; ++ci)
            #pragma unroll
            for (int r = 0; r < 4; ++r) {
                int d = (mi - 2) * 16 + lq * 4 + r;
                int n = w * 32 + ci * 16 + lr;
                float kk = acc[mi][ci][r];
                *(unsigned short*)(kmv + d * 272 + n * 2) = f2b(kk > 0.f ? kk + 1.f : __expf(kk));
            }
    #pragma unroll
    for (int mi = 4; mi < 6; ++mi)
        #pragma unroll
        for (int ci = 0; ci < 2; ++ci)
            #pragma unroll
            for (int r = 0; r < 4; ++r) {
                int e = (mi - 4) * 16 + lq * 4 + r;
                int n = w * 32 + ci * 16 + lr;
                *(unsigned short*)(kmv + (32 + e) * 272 + n * 2) = f2b(acc[mi][ci][r]);
            }
    __syncthreads();

    const size_t pb = (size_t)((b * NHEAD + h) * 256 + tile) * 1056;

    // qm -> global
    {
        char* qg = (char*)(qm_t + ((size_t)(b * NHEAD + h) * NNTOK + n0) * 32);
        int n = t >> 1, half = t & 1;
        const char* src = qs + n * 80 + half * 32;
        char* dst = qg + n * 64 + half * 32;
        *(float4*)dst = *(const float4*)src;
        *(float4*)(dst + 16) = *(const float4*)(src + 16);
    }

    // context quadrant per wave, K=128
    {
        int qr = w >> 1, qc = w & 1;
        accf4 cacc = (accf4){0.f, 0.f, 0.f, 0.f};
        #pragma unroll
        for (int kk = 0; kk < 4; ++kk) {
            bfrag8 a  = *(const bfrag8*)(kmv + (qr * 16 + lr) * 272 + kk * 64 + lq * 16);
            bfrag8 bb = *(const bfrag8*)(kmv + (32 + qc * 16 + lr) * 272 + kk * 64 + lq * 16);
            cacc = __builtin_amdgcn_mfma_f32_16x16x32_bf16(a, bb, cacc, 0, 0, 0);
        }
        #pragma unroll
        for (int r = 0; r < 4; ++r) {
            int d = qr * 16 + lq * 4 + r, e = qc * 16 + lr;
            part[pb + d * 32 + e] = cacc[r];
        }
    }

    // ksum partial
    {
        float* ksp = (float*)(lds + LDS_KSP_OFF);
        int d = t >> 3, oc = t & 7;
        float s = 0.f;
        for (int i = 0; i < 16; ++i)
            s += b2f(*(const unsigned short*)(kmv + d * 272 + (oc * 16 + i) * 2));
        ksp[d * 8 + oc] = s;
        __syncthreads();
        if (t < 32) {
            float s2 = 0.f;
            #pragma unroll
            for (int i = 0; i < 8; ++i) s2 += ksp[t * 8 + i];
            part[pb + 1024 + t] = s2;
        }
    }
}

// ============ Kernel 6: reduce 256 tile-records -> 16 per bh ============
__global__ __launch_bounds__(256) void reduce1(const float* __restrict__ part,
                                               float* __restrict__ part2) {
    int chunk = blockIdx.x, bh = blockIdx.y, t = threadIdx.x;
    const float* p = part + ((size_t)bh * 256 + chunk * 16) * 1056;
    for (int i = t; i < 1056; i += 256) {
        float s = 0.f;
        #pragma unroll
        for (int j = 0; j < 16; ++j) s += p[(size_t)j * 1056 + i];
        part2[((size_t)bh * 16 + chunk) * 1056 + i] = s;
    }
}

// ============ Kernel 7: build A (bf16) + finalize ksum ============
__global__ __launch_bounds__(256) void build_A(const float* __restrict__ w_out,
                                               const float* __restrict__ part2,
                                               unsigned short* __restrict__ Amat,
                                               float* __restrict__ ksum_g) {
    int ot = blockIdx.x, b = blockIdx.y, t = threadIdx.x;
    __shared__ float cs[NHEAD * HD * HD];
    for (int i = t; i < NHEAD * HD * HD; i += 256) {
        int hh = i >> 10, de = i & 1023;
        const float* p2 = part2 + (size_t)(b * NHEAD + hh) * 16 * 1056;
        float s = 0.f;
        #pragma unroll
        for (int c16 = 0; c16 < 16; ++c16) s += p2[(size_t)c16 * 1056 + de];
        cs[i] = s;
    }
    if (ot == 0) {
        const float* p2 = part2 + (size_t)(b * NHEAD + (t >> 5)) * 16 * 1056;
        float s = 0.f;
        #pragma unroll
        for (int c16 = 0; c16 < 16; ++c16) s += p2[(size_t)c16 * 1056 + 1024 + (t & 31)];
        ksum_g[b * CC + t] = s;
    }
    __syncthreads();
    int h = t >> 5, d = t & 31;
    for (int oi = 0; oi < 32; ++oi) {
        int o = ot * 32 + oi;
        const float* wrow = w_out + (size_t)o * CC + h * HD;
        float s = 0.f;
        #pragma unroll
        for (int e = 0; e < HD; ++e) s += wrow[e] * cs[h * 1024 + d * 32 + e];
        Amat[((size_t)(b * CC + o)) * CC + t] = f2b(s);
    }
}

// ============ Kernel 8: out = A @ (qm*den) + b_out + x, den fused in ============
#define LDSF_A   0
#define LDSF_Q   10240
#define LDSF_DEN 20480
#define LDSF_BO  20992
__global__ __launch_bounds__(256, 2) void final_out(
    const unsigned short* __restrict__ qm_t, const unsigned short* __restrict__ Amat,
    const float* __restrict__ ksum_g, const float* __restrict__ b_out,
    const float* __restrict__ x, float* __restrict__ out) {
    __shared__ char L[21504];
    int tile = blockIdx.x, mt = blockIdx.y, b = blockIdx.z;
    int n0 = tile * 128, t = threadIdx.x;
    int lane = t & 63, w = t >> 6, lr = lane & 15, lq = lane >> 4;
    int wm = (w >> 1) * 64, wn = (w & 1) * 64;
    accf4 acc[4][4];
    #pragma unroll
    for (int i = 0; i < 4; ++i)
        #pragma unroll
        for (int j = 0; j < 4; ++j) acc[i][j] = (accf4){0.f, 0.f, 0.f, 0.f};

    if (t < 128) ((float*)(L + LDSF_BO))[t] = b_out[mt * 128 + t];

    char* Al = L + LDSF_A;
    char* Ql = L + LDSF_Q;
    for (int h = 0; h < NHEAD; ++h) {
        int m = t >> 1, half = t & 1;
        const char* ag = (const char*)(Amat + ((size_t)(b * CC + mt * 128 + m) * CC + h * 32)) + half * 32;
        float4 av0 = *(const float4*)ag, av1 = *(const float4*)(ag + 16);
        const char* qg = (const char*)(qm_t + ((size_t)(b * NHEAD + h) * NNTOK + n0 + m) * 32) + half * 32;
        float4 qv0 = *(const float4*)qg, qv1 = *(const float4*)(qg + 16);
        float ksv = 0.f;
        if (t < 32) ksv = ksum_g[b * CC + h * 32 + t];
        __syncthreads();
        *(float4*)(Al + m * 80 + half * 32) = av0;
        *(float4*)(Al + m * 80 + half * 32 + 16) = av1;
        *(float4*)(Ql + m * 80 + half * 32) = qv0;
        *(float4*)(Ql + m * 80 + half * 32 + 16) = qv1;
        if (t < 32) ((float*)(L + LDSF_DEN))[t] = ksv;
        __syncthreads();
        {
            // fused den: dot(qm row, ksum) via pair of half-dots + shfl_xor
            int n = t >> 1, u = t & 1;
            const float* ksL = (const float*)(L + LDSF_DEN);
            char* p = Ql + n * 80 + u * 32;
            bfrag8 v0 = *(bfrag8*)p, v1 = *(bfrag8*)(p + 16);
            float sp = 0.f;
            #pragma unroll
            for (int e = 0; e < 8; ++e) {
                sp += b2f((unsigned short)v0[e]) * ksL[u * 16 + e];
                sp += b2f((unsigned short)v1[e]) * ksL[u * 16 + 8 + e];
            }
            float dot = sp + __shfl_xor(sp, 1);
            float dn = 1.0f / (dot + ATT_EPS);
            #pragma unroll
            for (int e = 0; e < 8; ++e) {
                v0[e] = (short)f2b(b2f((unsigned short)v0[e]) * dn);
                v1[e] = (short)f2b(b2f((unsigned short)v1[e]) * dn);
            }
            *(bfrag8*)p = v0;
            *(bfrag8*)(p + 16) = v1;
        }
        __syncthreads();
        bfrag8 bfr[4];
        #pragma unroll
        for (int ci = 0; ci < 4; ++ci) {
            int n = wn + ci * 16 + lr;
            bfr[ci] = *(const bfrag8*)(Ql + n * 80 + lq * 16);
        }
        #pragma unroll
        for (int mi = 0; mi < 4; ++mi) {
            bfrag8 a = *(const bfrag8*)(Al + (wm + mi * 16 + lr) * 80 + lq * 16);
            #pragma unroll
            for (int ci = 0; ci < 4; ++ci)
                acc[mi][ci] = __builtin_amdgcn_mfma_f32_16x16x32_bf16(a, bfr[ci], acc[mi][ci], 0, 0, 0);
        }
        __syncthreads();
    }

    const float* bo_s = (const float*)(L + LDSF_BO);
    #pragma unroll
    for (int mi = 0; mi < 4; ++mi)
        #pragma unroll
        for (int ci = 0; ci < 4; ++ci)
            #pragma unroll
            for (int r = 0; r < 4; ++r) {
                int ol = wm + mi * 16 + lq * 4 + r;
                int n = wn + ci * 16 + lr;
                size_t idx = ((size_t)(b * CC + mt * 128 + ol)) * NNTOK + n0 + n;
                out[idx] = acc[mi][ci][r] + bo_s[ol] + x[idx];
            }
}

extern "C" void kernel_launch(void* const* d_in, const int* in_sizes, int n_in,
                              void* d_out, int out_size, void* d_ws, size_t ws_size,
                              hipStream_t stream) {
    (void)in_sizes; (void)n_in; (void)out_size; (void)ws_size;
    const float* x      = (const float*)d_in[0];
    const float* gamma  = (const float*)d_in[1];
    const float* beta   = (const float*)d_in[2];
    const float* wq     = (const float*)d_in[3];
    const float* wk     = (const float*)d_in[4];
    const float* wv     = (const float*)d_in[5];
    const float* w_out  = (const float*)d_in[6];
    const float* b_out  = (const float*)d_in[7];
    float* out = (float*)d_out;
    float* ws  = (float*)d_ws;

    unsigned short* qm_t = (unsigned short*)(ws + WS_QMT);
    unsigned short* xn_t = (unsigned short*)(ws + WS_XNT);
    unsigned short* Wst  = (unsigned short*)(ws + WS_WST);
    float* part  = ws + WS_PART;
    float* part2 = ws + WS_PART2;   // aliases den region (read before any reuse)
    float* gnp   = ws + WS_GNP;
    float* scale = ws + WS_SCALE;
    float* shift = ws + WS_SHIFT;
    float* ksum  = ws + WS_KSUM;
    unsigned short* Amat = (unsigned short*)(ws + WS_AMAT);

    hipLaunchKernelGGL(gn_stats, dim3(BB * NGRP * KB_GN), dim3(256), 0, stream, x, gnp);
    hipLaunchKernelGGL(gn_finalize, dim3(1), dim3(256), 0, stream, gnp, gamma, beta, scale, shift);
    hipLaunchKernelGGL(prep_w, dim3(NHEAD), dim3(256), 0, stream, wq, wk, wv, Wst);
    hipLaunchKernelGGL(xn_prep, dim3(NNTOK / 64, BB), dim3(256), 0, stream, x, scale, shift, xn_t);
    hipLaunchKernelGGL(qkv_ctx, dim3(NNTOK / 128 * NHEAD * BB), dim3(256), 0, stream,
                       xn_t, Wst, qm_t, part);
    hipLaunchKernelGGL(reduce1, dim3(16, 16), dim3(256), 0, stream, part, part2);
    hipLaunchKernelGGL(build_A, dim3(8, BB), dim3(256), 0, stream, w_out, part2, Amat, ksum);
    hipLaunchKernelGGL(final_out, dim3(NNTOK / 128, 2, BB), dim3(256), 0, stream,
                       qm_t, Amat, ksum, b_out, x, out);
}

// Round 4
// 283.992 us; speedup vs baseline: 1.3132x; 1.0219x over previous
//
#include <hip/hip_runtime.h>
#include <math.h>

#define BB 2
#define CC 256
#define NHEAD 8
#define HD 32
#define NGRP 8
#define NNTOK 32768
#define ATT_EPS 1e-6f
#define GN_EPS 1e-5f
#define KB_GN 64

typedef __attribute__((ext_vector_type(8))) short bfrag8;   // 8 bf16
typedef __attribute__((ext_vector_type(4))) float accf4;    // MFMA C/D 16x16

__device__ __forceinline__ float b2f(unsigned short u) {
    unsigned int x = ((unsigned int)u) << 16;
    return __uint_as_float(x);
}
__device__ __forceinline__ unsigned short f2b(float f) {
    unsigned int x = __float_as_uint(f);
    unsigned int r = x + 0x7fffu + ((x >> 16) & 1u);
    return (unsigned short)(r >> 16);
}
__device__ __forceinline__ void gl_lds16(const void* g, void* s) {
    __builtin_amdgcn_global_load_lds(
        (const __attribute__((address_space(1))) unsigned int*)g,
        (__attribute__((address_space(3))) unsigned int*)s, 16, 0, 0);
}

// ---- workspace layout (float offsets) — identical to the verified map ----
#define WS_QMT   0ull            // bf16 [B][H][N][32]
#define WS_XNT   (WS_QMT + 8388608ull)    // bf16 [B][N][264] padded
#define WS_WST   (WS_XNT + 8650752ull)    // bf16 [H][24576] frag-linear (48KB/head)
#define WS_PART  (WS_WST + 101632ull)     // f32 [16 bh][256 tiles][1056]
#define WS_GNP   (WS_PART + 4325376ull)
#define WS_SCALE (WS_GNP + 2048ull)
#define WS_SHIFT (WS_SCALE + 512ull)
#define WS_CTX   (WS_SHIFT + 512ull)      // (unused, kept for layout stability)
#define WS_KSUM  (WS_CTX + 16384ull)      // f32 [B][H][32]
#define WS_AMAT  (WS_KSUM + 512ull)       // bf16 [B][256][256]
#define WS_DEN   (WS_AMAT + 65536ull)     // f32 region; part2 aliases this
#define WS_PART2 WS_DEN                   // f32 [16 bh][16][1056] = 270336 < 524288

// LDS for qkv_ctx: W tile 48KB frag-linear during main loop; epilogue overlay
// after barrier: kmv 64x272 @0, qs 128x80 @17408, ksp @27648 (29696 <= 49152)
#define LDS_QS_OFF  17408
#define LDS_KSP_OFF 27648
#define LDS_QKV_TOTAL 49152

// ============ Kernel 1: GroupNorm partial sums (verbatim) ============
__global__ __launch_bounds__(256) void gn_stats(const float* __restrict__ x,
                                                float* __restrict__ part) {
    int grp = blockIdx.x / KB_GN;
    int blk = blockIdx.x % KB_GN;
    const float* base = x + (size_t)grp * (CC / NGRP) * NNTOK + (size_t)blk * 16384;
    int t = threadIdx.x;
    float s = 0.f, s2 = 0.f;
    for (int i = 0; i < 16; ++i) {
        const float4 v = *(const float4*)(base + i * 1024 + t * 4);
        s  += v.x + v.y + v.z + v.w;
        s2 += v.x * v.x + v.y * v.y + v.z * v.z + v.w * v.w;
    }
    for (int off = 32; off; off >>= 1) {
        s  += __shfl_down(s, off);
        s2 += __shfl_down(s2, off);
    }
    __shared__ float ls[4], ls2[4];
    int wave = t >> 6;
    if ((t & 63) == 0) { ls[wave] = s; ls2[wave] = s2; }
    __syncthreads();
    if (t == 0) {
        part[(grp * KB_GN + blk) * 2 + 0] = ls[0] + ls[1] + ls[2] + ls[3];
        part[(grp * KB_GN + blk) * 2 + 1] = ls2[0] + ls2[1] + ls2[2] + ls2[3];
    }
}

// ============ Kernel 2: finalize GN (verbatim) ============
__global__ __launch_bounds__(256) void gn_finalize(const float* __restrict__ part,
                                                   const float* __restrict__ gamma,
                                                   const float* __restrict__ beta,
                                                   float* __restrict__ scale,
                                                   float* __restrict__ shift) {
    __shared__ float mean_s[16], rstd_s[16];
    int t = threadIdx.x;
    if (t < 16) {
        float s = 0.f, s2 = 0.f;
        for (int i = 0; i < KB_GN; ++i) {
            s  += part[(t * KB_GN + i) * 2 + 0];
            s2 += part[(t * KB_GN + i) * 2 + 1];
        }
        const float inv = 1.0f / (float)((CC / NGRP) * NNTOK);
        float m = s * inv;
        float var = s2 * inv - m * m;
        mean_s[t] = m;
        rstd_s[t] = rsqrtf(var + GN_EPS);
    }
    __syncthreads();
    for (int idx = t; idx < BB * CC; idx += 256) {
        int b = idx / CC, c = idx % CC;
        int grp = b * NGRP + c / (CC / NGRP);
        float sc = gamma[c] * rstd_s[grp];
        scale[idx] = sc;
        shift[idx] = beta[c] - mean_s[grp] * sc;
    }
}

// ============ Kernel 3: Wst frag-linear: [h][kc][mi][lane][8e] bf16 (verbatim) ============
__global__ __launch_bounds__(256) void prep_w(const float* __restrict__ wq,
                                              const float* __restrict__ wk,
                                              const float* __restrict__ wv,
                                              unsigned short* __restrict__ Wst) {
    int h = blockIdx.x, t = threadIdx.x;
    const float* Ws[3] = {wq, wk, wv};
    for (int i = t; i < 24576; i += 256) {
        int e = i & 7;
        int chunk = i >> 3;
        int lane = chunk & 63;
        int kcmi = chunk >> 6;
        int mi = kcmi % 6;
        int kc = kcmi / 6;
        int lr = lane & 15, lq = lane >> 4;
        int row = mi * 16 + lr;
        int col = kc * 32 + lq * 8 + e;
        float v = Ws[row >> 5][(size_t)(h * 32 + (row & 31)) * CC + col];
        Wst[(size_t)h * 24576 + i] = f2b(v);
    }
}

// ============ Kernel 4: xn_t[b][n][264] bf16 (verbatim) ============
__global__ __launch_bounds__(256) void xn_prep(const float* __restrict__ x,
                                               const float* __restrict__ scale,
                                               const float* __restrict__ shift,
                                               unsigned short* __restrict__ xn_t) {
    __shared__ unsigned short xt[64][264];
    int b = blockIdx.y, n0 = blockIdx.x * 64, t = threadIdx.x;
    int col4 = (t & 15) * 4;
    for (int i = 0; i < 16; ++i) {
        int c = (t >> 4) + i * 16;
        float sc = scale[b * CC + c], sh = shift[b * CC + c];
        const float4 v = *(const float4*)(x + (size_t)(b * CC + c) * NNTOK + n0 + col4);
        xt[col4 + 0][c] = f2b(v.x * sc + sh);
        xt[col4 + 1][c] = f2b(v.y * sc + sh);
        xt[col4 + 2][c] = f2b(v.z * sc + sh);
        xt[col4 + 3][c] = f2b(v.w * sc + sh);
    }
    __syncthreads();
    int n = t >> 2, q = t & 3;
    const char* src = (const char*)&xt[n][0] + q * 128;
    char* dst = (char*)(xn_t + ((size_t)b * NNTOK + n0 + n) * 264) + q * 128;
    #pragma unroll
    for (int i = 0; i < 8; ++i)
        *(float4*)(dst + i * 16) = *(const float4*)(src + i * 16);
}

// ============ Kernel 5: fused QKV MFMA + elu + ctx/ksum partials (R3 verbatim) ============
__global__ __launch_bounds__(256, 3) void qkv_ctx(
    const unsigned short* __restrict__ xn_t, const unsigned short* __restrict__ Wst,
    unsigned short* __restrict__ qm_t, float* __restrict__ part) {
    __shared__ char lds[LDS_QKV_TOTAL];
    const int id = blockIdx.x;
    const int xcd = id & 7;
    const int j = id >> 3;
    const int h = j & 7;
    const int rem = j >> 3;                 // 0..63
    const int tile = xcd * 32 + (rem & 31);
    const int b = rem >> 5;
    const int t = threadIdx.x;
    const int lane = t & 63, w = t >> 6;
    const int lr = lane & 15, lq = lane >> 4;
    const int n0 = tile * 128;

    // stage W tile (48KB) frag-linear; LDS dest wave-uniform + lane*16
    {
        const char* wg = (const char*)(Wst + (size_t)h * 24576);
        for (int jj = w; jj < 48; jj += 4)
            gl_lds16(wg + jj * 1024 + lane * 16, lds + jj * 1024);
    }
    __syncthreads();

    accf4 acc[6][2];
    #pragma unroll
    for (int i = 0; i < 6; ++i)
        #pragma unroll
        for (int jj = 0; jj < 2; ++jj) acc[i][jj] = (accf4){0.f, 0.f, 0.f, 0.f};

    // this thread's two xn_t rows (ci=0,1); 16B chunk selected by lq, kc
    const unsigned short* xr0 = xn_t + ((size_t)b * NNTOK + n0 + w * 32 + lr) * 264 + lq * 8;
    const unsigned short* xr1 = xr0 + 16 * 264;
    const char* wl = lds;

    // prefetch kc=0 fragments
    bfrag8 wnx[6], bnx[2];
    #pragma unroll
    for (int mi = 0; mi < 6; ++mi)
        wnx[mi] = *(const bfrag8*)(wl + (0 * 6 + mi) * 1024 + lane * 16);
    bnx[0] = *(const bfrag8*)xr0;
    bnx[1] = *(const bfrag8*)xr1;

    #pragma unroll
    for (int kc = 0; kc < 8; ++kc) {
        bfrag8 wcur[6];
        #pragma unroll
        for (int mi = 0; mi < 6; ++mi) wcur[mi] = wnx[mi];
        bfrag8 bcur[2] = {bnx[0], bnx[1]};
        if (kc < 7) {
            #pragma unroll
            for (int mi = 0; mi < 6; ++mi)
                wnx[mi] = *(const bfrag8*)(wl + ((kc + 1) * 6 + mi) * 1024 + lane * 16);
            bnx[0] = *(const bfrag8*)(xr0 + (kc + 1) * 32);
            bnx[1] = *(const bfrag8*)(xr1 + (kc + 1) * 32);
        }
        #pragma unroll
        for (int mi = 0; mi < 6; ++mi)
            #pragma unroll
            for (int ci = 0; ci < 2; ++ci)
                acc[mi][ci] = __builtin_amdgcn_mfma_f32_16x16x32_bf16(wcur[mi], bcur[ci], acc[mi][ci], 0, 0, 0);
    }
    __syncthreads();   // all waves done reading W region — overlay now safe

    // epilogue (verified math, overlay pointers)
    char* kmv = lds;                 // km rows 0..31, v rows 32..63, stride 272
    char* qs  = lds + LDS_QS_OFF;    // qm [n 128][80 B]
    #pragma unroll
    for (int mi = 0; mi < 2; ++mi)
        #pragma unroll
        for (int ci = 0; ci < 2; ++ci)
            #pragma unroll
            for (int r = 0; r < 4; ++r) {
                int d = mi * 16 + lq * 4 + r;
                int n = w * 32 + ci * 16 + lr;
                float q = acc[mi][ci][r];
                *(unsigned short*)(qs + n * 80 + d * 2) = f2b(q > 0.f ? q + 1.f : __expf(q));
            }
    #pragma unroll
    for (int mi = 2; mi < 4; ++mi)
        #pragma unroll
        for (int ci = 0; ci < 2; ++ci)
            #pragma unroll
            for (int r = 0; r < 4; ++r) {
                int d = (mi - 2) * 16 + lq * 4 + r;
                int n = w * 32 + ci * 16 + lr;
                float kk = acc[mi][ci][r];
                *(unsigned short*)(kmv + d * 272 + n * 2) = f2b(kk > 0.f ? kk + 1.f : __expf(kk));
            }
    #pragma unroll
    for (int mi = 4; mi < 6; ++mi)
        #pragma unroll
        for (int ci = 0; ci < 2; ++ci)
            #pragma unroll
            for (int r = 0; r < 4; ++r) {
                int e = (mi - 4) * 16 + lq * 4 + r;
                int n = w * 32 + ci * 16 + lr;
                *(unsigned short*)(kmv + (32 + e) * 272 + n * 2) = f2b(acc[mi][ci][r]);
            }
    __syncthreads();

    const size_t pb = (size_t)((b * NHEAD + h) * 256 + tile) * 1056;

    // qm -> global
    {
        char* qg = (char*)(qm_t + ((size_t)(b * NHEAD + h) * NNTOK + n0) * 32);
        int n = t >> 1, half = t & 1;
        const char* src = qs + n * 80 + half * 32;
        char* dst = qg + n * 64 + half * 32;
        *(float4*)dst = *(const float4*)src;
        *(float4*)(dst + 16) = *(const float4*)(src + 16);
    }

    // context quadrant per wave, K=128
    {
        int qr = w >> 1, qc = w & 1;
        accf4 cacc = (accf4){0.f, 0.f, 0.f, 0.f};
        #pragma unroll
        for (int kk = 0; kk < 4; ++kk) {
            bfrag8 a  = *(const bfrag8*)(kmv + (qr * 16 + lr) * 272 + kk * 64 + lq * 16);
            bfrag8 bb = *(const bfrag8*)(kmv + (32 + qc * 16 + lr) * 272 + kk * 64 + lq * 16);
            cacc = __builtin_amdgcn_mfma_f32_16x16x32_bf16(a, bb, cacc, 0, 0, 0);
        }
        #pragma unroll
        for (int r = 0; r < 4; ++r) {
            int d = qr * 16 + lq * 4 + r, e = qc * 16 + lr;
            part[pb + d * 32 + e] = cacc[r];
        }
    }

    // ksum partial
    {
        float* ksp = (float*)(lds + LDS_KSP_OFF);
        int d = t >> 3, oc = t & 7;
        float s = 0.f;
        for (int i = 0; i < 16; ++i)
            s += b2f(*(const unsigned short*)(kmv + d * 272 + (oc * 16 + i) * 2));
        ksp[d * 8 + oc] = s;
        __syncthreads();
        if (t < 32) {
            float s2 = 0.f;
            #pragma unroll
            for (int i = 0; i < 8; ++i) s2 += ksp[t * 8 + i];
            part[pb + 1024 + t] = s2;
        }
    }
}

// ============ Kernel 6: reduce 256 tile-records -> 16 per bh (float4) ============
__global__ __launch_bounds__(256) void reduce1(const float* __restrict__ part,
                                               float* __restrict__ part2) {
    int chunk = blockIdx.x, bh = blockIdx.y, t = threadIdx.x;
    const float* p = part + ((size_t)bh * 256 + chunk * 16) * 1056;
    float* q = part2 + ((size_t)bh * 16 + chunk) * 1056;
    for (int i4 = t; i4 < 264; i4 += 256) {
        float4 s = (float4){0.f, 0.f, 0.f, 0.f};
        #pragma unroll
        for (int j = 0; j < 16; ++j) {
            const float4 v = *(const float4*)(p + (size_t)j * 1056 + i4 * 4);
            s.x += v.x; s.y += v.y; s.z += v.z; s.w += v.w;
        }
        *(float4*)(q + i4 * 4) = s;
    }
}

// ============ Kernel 7: build A (bf16) + finalize ksum (verbatim) ============
__global__ __launch_bounds__(256) void build_A(const float* __restrict__ w_out,
                                               const float* __restrict__ part2,
                                               unsigned short* __restrict__ Amat,
                                               float* __restrict__ ksum_g) {
    int ot = blockIdx.x, b = blockIdx.y, t = threadIdx.x;
    __shared__ float cs[NHEAD * HD * HD];
    for (int i = t; i < NHEAD * HD * HD; i += 256) {
        int hh = i >> 10, de = i & 1023;
        const float* p2 = part2 + (size_t)(b * NHEAD + hh) * 16 * 1056;
        float s = 0.f;
        #pragma unroll
        for (int c16 = 0; c16 < 16; ++c16) s += p2[(size_t)c16 * 1056 + de];
        cs[i] = s;
    }
    if (ot == 0) {
        const float* p2 = part2 + (size_t)(b * NHEAD + (t >> 5)) * 16 * 1056;
        float s = 0.f;
        #pragma unroll
        for (int c16 = 0; c16 < 16; ++c16) s += p2[(size_t)c16 * 1056 + 1024 + (t & 31)];
        ksum_g[b * CC + t] = s;
    }
    __syncthreads();
    int h = t >> 5, d = t & 31;
    for (int oi = 0; oi < 32; ++oi) {
        int o = ot * 32 + oi;
        const float* wrow = w_out + (size_t)o * CC + h * HD;
        float s = 0.f;
        #pragma unroll
        for (int e = 0; e < HD; ++e) s += wrow[e] * cs[h * 1024 + d * 32 + e];
        Amat[((size_t)(b * CC + o)) * CC + t] = f2b(s);
    }
}

// ============ Kernel 8: out = A @ (qm*den) + b_out + x ============
// Rewritten: den computed from the load registers (pair shfl_xor) BEFORE any
// barrier; qm written to LDS pre-scaled (kills the in-place scale pass and one
// barrier); 2 barriers/head; next head's A/qm prefetched during MFMA;
// launch_bounds(256,4): 22KB LDS -> 4 blocks/CU (was 2).
#define LDSF_A   0
#define LDSF_Q   10240
#define LDSF_BO  20480      // 128 f32
#define LDSF_KS  20992      // 256 f32
#define LDSF_TOT 22016
__global__ __launch_bounds__(256, 4) void final_out(
    const unsigned short* __restrict__ qm_t, const unsigned short* __restrict__ Amat,
    const float* __restrict__ ksum_g, const float* __restrict__ b_out,
    const float* __restrict__ x, float* __restrict__ out) {
    __shared__ char L[LDSF_TOT];
    int tile = blockIdx.x, mt = blockIdx.y, b = blockIdx.z;
    int n0 = tile * 128, t = threadIdx.x;
    int lane = t & 63, w = t >> 6, lr = lane & 15, lq = lane >> 4;
    int wm = (w >> 1) * 64, wn = (w & 1) * 64;
    accf4 acc[4][4];
    #pragma unroll
    for (int i = 0; i < 4; ++i)
        #pragma unroll
        for (int j = 0; j < 4; ++j) acc[i][j] = (accf4){0.f, 0.f, 0.f, 0.f};

    if (t < 128) ((float*)(L + LDSF_BO))[t] = b_out[mt * 128 + t];
    ((float*)(L + LDSF_KS))[t] = ksum_g[b * CC + t];

    char* Al = L + LDSF_A;
    char* Ql = L + LDSF_Q;
    const int m = t >> 1, half = t & 1;
    // per-thread global bases; per-head strides: A +64 B, qm +NNTOK*64 B
    const char* ag = (const char*)(Amat + (size_t)(b * CC + mt * 128 + m) * CC) + half * 32;
    const char* qg = (const char*)(qm_t + ((size_t)b * NHEAD * NNTOK + (size_t)(n0 + m)) * 32) + half * 32;

    // prefetch h=0
    bfrag8 a0 = *(const bfrag8*)ag;
    bfrag8 a1 = *(const bfrag8*)(ag + 16);
    bfrag8 q0 = *(const bfrag8*)qg;
    bfrag8 q1 = *(const bfrag8*)(qg + 16);

    __syncthreads();   // ksum/bo visible

    for (int h = 0; h < NHEAD; ++h) {
        // den for row m from registers + ksum LDS (pair covers all 32 channels)
        const float* ks = (const float*)(L + LDSF_KS) + h * 32 + half * 16;
        float sp = 0.f;
        #pragma unroll
        for (int e = 0; e < 8; ++e) {
            sp += b2f((unsigned short)q0[e]) * ks[e];
            sp += b2f((unsigned short)q1[e]) * ks[8 + e];
        }
        float dot = sp + __shfl_xor(sp, 1);
        float dn = 1.0f / (dot + ATT_EPS);

        __syncthreads();   // previous head's MFMA done reading LDS
        *(bfrag8*)(Al + m * 80 + half * 32) = a0;
        *(bfrag8*)(Al + m * 80 + half * 32 + 16) = a1;
        bfrag8 s0, s1;
        #pragma unroll
        for (int e = 0; e < 8; ++e) {
            s0[e] = (short)f2b(b2f((unsigned short)q0[e]) * dn);
            s1[e] = (short)f2b(b2f((unsigned short)q1[e]) * dn);
        }
        *(bfrag8*)(Ql + m * 80 + half * 32) = s0;
        *(bfrag8*)(Ql + m * 80 + half * 32 + 16) = s1;
        __syncthreads();   // tiles ready

        if (h < 7) {       // prefetch next head during MFMA
            a0 = *(const bfrag8*)(ag + (h + 1) * 64);
            a1 = *(const bfrag8*)(ag + (h + 1) * 64 + 16);
            q0 = *(const bfrag8*)(qg + (size_t)(h + 1) * NNTOK * 64);
            q1 = *(const bfrag8*)(qg + (size_t)(h + 1) * NNTOK * 64 + 16);
        }

        bfrag8 bfr[4];
        #pragma unroll
        for (int ci = 0; ci < 4; ++ci) {
            int n = wn + ci * 16 + lr;
            bfr[ci] = *(const bfrag8*)(Ql + n * 80 + lq * 16);
        }
        #pragma unroll
        for (int mi = 0; mi < 4; ++mi) {
            bfrag8 a = *(const bfrag8*)(Al + (wm + mi * 16 + lr) * 80 + lq * 16);
            #pragma unroll
            for (int ci = 0; ci < 4; ++ci)
                acc[mi][ci] = __builtin_amdgcn_mfma_f32_16x16x32_bf16(a, bfr[ci], acc[mi][ci], 0, 0, 0);
        }
    }

    const float* bo_s = (const float*)(L + LDSF_BO);
    #pragma unroll
    for (int mi = 0; mi < 4; ++mi)
        #pragma unroll
        for (int ci = 0; ci < 4; ++ci)
            #pragma unroll
            for (int r = 0; r < 4; ++r) {
                int ol = wm + mi * 16 + lq * 4 + r;
                int n = wn + ci * 16 + lr;
                size_t idx = ((size_t)(b * CC + mt * 128 + ol)) * NNTOK + n0 + n;
                out[idx] = acc[mi][ci][r] + bo_s[ol] + x[idx];
            }
}

extern "C" void kernel_launch(void* const* d_in, const int* in_sizes, int n_in,
                              void* d_out, int out_size, void* d_ws, size_t ws_size,
                              hipStream_t stream) {
    (void)in_sizes; (void)n_in; (void)out_size; (void)ws_size;
    const float* x      = (const float*)d_in[0];
    const float* gamma  = (const float*)d_in[1];
    const float* beta   = (const float*)d_in[2];
    const float* wq     = (const float*)d_in[3];
    const float* wk     = (const float*)d_in[4];
    const float* wv     = (const float*)d_in[5];
    const float* w_out  = (const float*)d_in[6];
    const float* b_out  = (const float*)d_in[7];
    float* out = (float*)d_out;
    float* ws  = (float*)d_ws;

    unsigned short* qm_t = (unsigned short*)(ws + WS_QMT);
    unsigned short* xn_t = (unsigned short*)(ws + WS_XNT);
    unsigned short* Wst  = (unsigned short*)(ws + WS_WST);
    float* part  = ws + WS_PART;
    float* part2 = ws + WS_PART2;   // aliases den region (read before any reuse)
    float* gnp   = ws + WS_GNP;
    float* scale = ws + WS_SCALE;
    float* shift = ws + WS_SHIFT;
    float* ksum  = ws + WS_KSUM;
    unsigned short* Amat = (unsigned short*)(ws + WS_AMAT);

    hipLaunchKernelGGL(gn_stats, dim3(BB * NGRP * KB_GN), dim3(256), 0, stream, x, gnp);
    hipLaunchKernelGGL(gn_finalize, dim3(1), dim3(256), 0, stream, gnp, gamma, beta, scale, shift);
    hipLaunchKernelGGL(prep_w, dim3(NHEAD), dim3(256), 0, stream, wq, wk, wv, Wst);
    hipLaunchKernelGGL(xn_prep, dim3(NNTOK / 64, BB), dim3(256), 0, stream, x, scale, shift, xn_t);
    hipLaunchKernelGGL(qkv_ctx, dim3(NNTOK / 128 * NHEAD * BB), dim3(256), 0, stream,
                       xn_t, Wst, qm_t, part);
    hipLaunchKernelGGL(reduce1, dim3(16, 16), dim3(256), 0, stream, part, part2);
    hipLaunchKernelGGL(build_A, dim3(8, BB), dim3(256), 0, stream, w_out, part2, Amat, ksum);
    hipLaunchKernelGGL(final_out, dim3(NNTOK / 128, 2, BB), dim3(256), 0, stream,
                       qm_t, Amat, ksum, b_out, x, out);
}